// Round 11
// baseline (261.532 us; speedup 1.0000x reference)
//
#include <hip/hip_runtime.h>
#include <hip/hip_bf16.h>
#include <hip/hip_cooperative_groups.h>

namespace cg = cooperative_groups;

// Dims fixed by the reference
#define BB 8
#define NN 2048
#define DF 256
#define HH 64

using bf16x8 = __attribute__((ext_vector_type(8))) short;
using f32x4  = __attribute__((ext_vector_type(4))) float;
typedef unsigned short u16;

static __device__ __forceinline__ short bf_hi_bits(float v, float* hi_f) {
    __hip_bfloat16 h = __float2bfloat16(v);
    *hi_f = __bfloat162float(h);
    return __builtin_bit_cast(short, h);
}

// ---------------------------------------------------------------------------
// ONE cooperative kernel, 256 blocks x 512 threads (1 block/CU co-resident).
// Rationale: three structurally different qk variants all measured 40-46 us
// against a ~10 us static model -> the invariant is per-launch overhead /
// inter-kernel serialization, not kernel work. Fusing wprep+qk+attn into one
// launch removes 2 launch boundaries and gives direct top-5 visibility of
// our total GPU time.
//   Phase A: wprep (blocks 0-7; one W fragment per wave) -> Wsp (pi-head).
//   Phase B: qk -- r2's proven direct-global-Wsp variant (no LDS/barriers;
//            Wsp = 128 KB, L2-resident per XCD). Wave t<1024 owns 16 rows.
//   Phase C: attn -- r4's proven 2-pass 64-col-strip structure verbatim
//            (best measured attn), 1-D mapping strip=bid>>3, b=bid&7.
// Wsp aliasing is ordered by the grid.sync()s: A writes, B reads, C pass-2
// overwrites. Workspace stays at the proven 8 MB (Qs/Ks only).
// ---------------------------------------------------------------------------
__global__ __launch_bounds__(512, 2) void fused_kernel(
    const float* __restrict__ f, const float* __restrict__ x,
    const float* __restrict__ log_eps,
    const float* __restrict__ Wq, const float* __restrict__ Wk,
    u16* __restrict__ Qs, u16* __restrict__ Ks,
    float* __restrict__ y, float* __restrict__ pi)
{
    __shared__ float xs[NN * 3];             // 24 KB (phase C)
    __shared__ float cred[64];               // strip colsums (phase C)
    __shared__ float yred[8 * 4 * 16 * 3];   // 6 KB (phase C)

    cg::grid_group grid = cg::this_grid();

    const int tid  = threadIdx.x;
    const int bid  = blockIdx.x;
    const int wave = tid >> 6;               // 0..7
    const int lane = tid & 63;
    const int l15  = lane & 15;
    const int quad = lane >> 4;

    u16* Wsp = (u16*)pi;                     // 128 KB pi-head alias

    // ================= Phase A: wprep (blocks 0-7) =================
    if (bid < 8) {
        const int fid = bid * 8 + wave;      // 0..63 = kc*8 + ct
        const int kc = fid >> 3, ct = fid & 7;
        const float* W = (ct < 4) ? Wq : Wk;
        const int col  = (ct & 3) * 16 + l15;
        const int krow = kc * 32 + quad * 8;
        bf16x8 hv, lv;
#pragma unroll
        for (int j = 0; j < 8; ++j) {
            float w = W[(size_t)(krow + j) * HH + col];
            float hf, d;
            hv[j] = bf_hi_bits(w, &hf);
            lv[j] = bf_hi_bits(w - hf, &d);
        }
        u16* dst = Wsp + (size_t)fid * 1024 + lane * 8;
        *(bf16x8*)dst         = hv;
        *(bf16x8*)(dst + 512) = lv;
    }
    grid.sync();

    // ================= Phase B: qk projection =================
    {
        const int t = bid * 8 + wave;        // grid wave id
        if (t < 1024) {                      // 1024 x 16 rows = 16384
            const int row0 = t * 16;
            const int b    = row0 >> 11;
            f32x4 acc[8] = {};
            const float* frow = f + (size_t)(row0 + l15) * DF + quad * 8;

#pragma unroll
            for (int kc = 0; kc < 8; ++kc) {
                float4 a0 = *(const float4*)(frow + kc * 32);
                float4 a1 = *(const float4*)(frow + kc * 32 + 4);
                bf16x8 ah, al;
#pragma unroll
                for (int e = 0; e < 4; ++e) {
                    float hf, d;
                    float v0 = (&a0.x)[e], v1 = (&a1.x)[e];
                    ah[e]     = bf_hi_bits(v0, &hf);
                    al[e]     = bf_hi_bits(v0 - hf, &d);
                    ah[e + 4] = bf_hi_bits(v1, &hf);
                    al[e + 4] = bf_hi_bits(v1 - hf, &d);
                }
                const u16* wb = Wsp + (size_t)kc * 8192 + lane * 8;
#pragma unroll
                for (int ct = 0; ct < 8; ++ct) {
                    bf16x8 bh = *(const bf16x8*)(wb + ct * 1024);
                    bf16x8 bl = *(const bf16x8*)(wb + ct * 1024 + 512);
                    acc[ct] = __builtin_amdgcn_mfma_f32_16x16x32_bf16(ah, bh, acc[ct], 0, 0, 0);
                    acc[ct] = __builtin_amdgcn_mfma_f32_16x16x32_bf16(ah, bl, acc[ct], 0, 0, 0);
                    acc[ct] = __builtin_amdgcn_mfma_f32_16x16x32_bf16(al, bh, acc[ct], 0, 0, 0);
                }
            }

            const float le = log_eps[b];
#pragma unroll
            for (int ct = 0; ct < 8; ++ct) {
                const int h = (ct & 3) * 16 + l15;
                const float wlast = (ct < 4 ? Wq : Wk)[DF * HH + h];
                u16* out = (ct < 4) ? Qs : Ks;
                const float sc = (ct < 4) ? 0.125f : 1.0f;
#pragma unroll
                for (int r = 0; r < 4; ++r) {
                    int bn = row0 + quad * 4 + r;
                    float v = (acc[ct][r] + le * wlast) * sc;
                    float hf, d;
                    short hb = bf_hi_bits(v, &hf);
                    short lb = bf_hi_bits(v - hf, &d);
                    out[(size_t)bn * 128 + h]      = (u16)hb;
                    out[(size_t)bn * 128 + 64 + h] = (u16)lb;
                }
            }
        }
    }
    grid.sync();

    // ================= Phase C: attention (r4 verbatim) =================
    const int strip = bid >> 3;              // 0..31
    const int b     = bid & 7;               // 0..7
    const int m0    = strip * 64;

    if (tid < 64) cred[tid] = 0.f;
    for (int i = tid; i < NN * 3; i += 512) xs[i] = x[(size_t)b * NN * 3 + i];
    __syncthreads();

    // K-strip B-fragments (4 col-tiles), resident
    bf16x8 bh[4][2], bl[4][2];
    {
        const u16* Kb = Ks + ((size_t)b * NN + m0) * 128;
#pragma unroll
        for (int ct = 0; ct < 4; ++ct) {
            const u16* kr = Kb + (size_t)(ct * 16 + l15) * 128;
#pragma unroll
            for (int ks = 0; ks < 2; ++ks) {
                int k0 = ks * 32 + quad * 8;
                bh[ct][ks] = *(const bf16x8*)(kr + k0);
                bl[ct][ks] = *(const bf16x8*)(kr + 64 + k0);
            }
        }
    }

    const u16* Qb = Qs + (size_t)b * NN * 128;
    float cs[4] = {0.f, 0.f, 0.f, 0.f};
    float yacc[4][3] = {};

    // ---- Pass 1: column sums + y accumulation ----
    for (int rt = 0; rt < 8; ++rt) {
#pragma unroll
        for (int sr = 0; sr < 2; ++sr) {
            const int row0 = rt * 256 + wave * 32 + sr * 16;
            const u16* qr = Qb + (size_t)(row0 + l15) * 128;
            bf16x8 ah[2], al[2];
#pragma unroll
            for (int ks = 0; ks < 2; ++ks) {
                int k0 = ks * 32 + quad * 8;
                ah[ks] = *(const bf16x8*)(qr + k0);
                al[ks] = *(const bf16x8*)(qr + 64 + k0);
            }
            float xv[4][3];
#pragma unroll
            for (int r = 0; r < 4; ++r) {
                int row = row0 + quad * 4 + r;
                xv[r][0] = xs[row * 3 + 0];
                xv[r][1] = xs[row * 3 + 1];
                xv[r][2] = xs[row * 3 + 2];
            }
#pragma unroll
            for (int ct = 0; ct < 4; ++ct) {
                f32x4 acc = {0.f, 0.f, 0.f, 0.f};
#pragma unroll
                for (int ks = 0; ks < 2; ++ks) {
                    acc = __builtin_amdgcn_mfma_f32_16x16x32_bf16(ah[ks], bh[ct][ks], acc, 0, 0, 0);
                    acc = __builtin_amdgcn_mfma_f32_16x16x32_bf16(ah[ks], bl[ct][ks], acc, 0, 0, 0);
                    acc = __builtin_amdgcn_mfma_f32_16x16x32_bf16(al[ks], bh[ct][ks], acc, 0, 0, 0);
                }
                float s = 0.f;
#pragma unroll
                for (int r = 0; r < 4; ++r) {
                    float v = __expf(acc[r]);
                    s += v;
                    yacc[ct][0] = fmaf(v, xv[r][0], yacc[ct][0]);
                    yacc[ct][1] = fmaf(v, xv[r][1], yacc[ct][1]);
                    yacc[ct][2] = fmaf(v, xv[r][2], yacc[ct][2]);
                }
                cs[ct] += s;
            }
        }
    }

    // deferred cross-quad reductions, then LDS
#pragma unroll
    for (int ct = 0; ct < 4; ++ct) {
        cs[ct] += __shfl_xor(cs[ct], 16);
        cs[ct] += __shfl_xor(cs[ct], 32);
#pragma unroll
        for (int d = 0; d < 3; ++d) {
            yacc[ct][d] += __shfl_xor(yacc[ct][d], 16);
            yacc[ct][d] += __shfl_xor(yacc[ct][d], 32);
        }
    }
    if (quad == 0) {
#pragma unroll
        for (int ct = 0; ct < 4; ++ct) {
            atomicAdd(&cred[ct * 16 + l15], cs[ct]);
#pragma unroll
            for (int d = 0; d < 3; ++d)
                yred[((wave * 4 + ct) * 16 + l15) * 3 + d] = yacc[ct][d];
        }
    }
    __syncthreads();

    if (tid < 192) {                         // 64 cols x 3 dims
        int c = tid / 3, d = tid - c * 3;
        int ct = c >> 4, cl = c & 15;
        float s = 0.f;
#pragma unroll
        for (int w = 0; w < 8; ++w)
            s += yred[((w * 4 + ct) * 16 + cl) * 3 + d];
        y[((size_t)b * NN + m0 + c) * 3 + d] = s / cred[c];
    }

    const float invN = 1.0f / (float)NN;
    float iv[4];
#pragma unroll
    for (int ct = 0; ct < 4; ++ct) iv[ct] = invN / cred[ct * 16 + l15];
    float* pib = pi + (size_t)b * NN * NN + m0;

    // ---- Pass 2: recompute, write pi (plain stores -> L2 coalesces) ----
    for (int rt = 0; rt < 8; ++rt) {
#pragma unroll
        for (int sr = 0; sr < 2; ++sr) {
            const int row0 = rt * 256 + wave * 32 + sr * 16;
            const u16* qr = Qb + (size_t)(row0 + l15) * 128;
            bf16x8 ah[2], al[2];
#pragma unroll
            for (int ks = 0; ks < 2; ++ks) {
                int k0 = ks * 32 + quad * 8;
                ah[ks] = *(const bf16x8*)(qr + k0);
                al[ks] = *(const bf16x8*)(qr + 64 + k0);
            }
#pragma unroll
            for (int ct = 0; ct < 4; ++ct) {
                f32x4 acc = {0.f, 0.f, 0.f, 0.f};
#pragma unroll
                for (int ks = 0; ks < 2; ++ks) {
                    acc = __builtin_amdgcn_mfma_f32_16x16x32_bf16(ah[ks], bh[ct][ks], acc, 0, 0, 0);
                    acc = __builtin_amdgcn_mfma_f32_16x16x32_bf16(ah[ks], bl[ct][ks], acc, 0, 0, 0);
                    acc = __builtin_amdgcn_mfma_f32_16x16x32_bf16(al[ks], bh[ct][ks], acc, 0, 0, 0);
                }
                float* op = pib + (size_t)(row0 + quad * 4) * NN + ct * 16 + l15;
#pragma unroll
                for (int r = 0; r < 4; ++r)
                    op[(size_t)r * NN] = __expf(acc[r]) * iv[ct];
            }
        }
    }
}

// ---------------------------------------------------------------------------
extern "C" void kernel_launch(void* const* d_in, const int* in_sizes, int n_in,
                              void* d_out, int out_size, void* d_ws, size_t ws_size,
                              hipStream_t stream) {
    const float* f  = (const float*)d_in[0];
    const float* x  = (const float*)d_in[1];
    const float* le = (const float*)d_in[2];
    const float* Wq = (const float*)d_in[3];
    const float* Wk = (const float*)d_in[4];

    float* y  = (float*)d_out;                       // (B, N, 3)
    float* pi = (float*)d_out + (size_t)BB * NN * 3; // (B, N, N)

    // Workspace: exactly the proven 8 MB (split-bf16 Q and K).
    u16* Qs = (u16*)d_ws;                            // 4 MB
    u16* Ks = Qs + (size_t)BB * NN * 128;            // 4 MB

    void* args[] = {(void*)&f, (void*)&x, (void*)&le, (void*)&Wq, (void*)&Wk,
                    (void*)&Qs, (void*)&Ks, (void*)&y, (void*)&pi};
    hipLaunchCooperativeKernel((const void*)fused_kernel, dim3(256), dim3(512),
                               args, 0, stream);
}

// Round 12
// 196.911 us; speedup vs baseline: 1.3282x; 1.3282x over previous
//
#include <hip/hip_runtime.h>
#include <hip/hip_bf16.h>

// Dims fixed by the reference
#define BB 8
#define NN 2048
#define DF 256
#define HH 64

using bf16x8 = __attribute__((ext_vector_type(8))) short;
using f32x4  = __attribute__((ext_vector_type(4))) float;
typedef unsigned short u16;

static __device__ __forceinline__ short bf_hi_bits(float v, float* hi_f) {
    __hip_bfloat16 h = __float2bfloat16(v);
    *hi_f = __bfloat162float(h);
    return __builtin_bit_cast(short, h);
}

// ---------------------------------------------------------------------------
// Kernel 1: Q/K projection with IN-BLOCK W conversion (wprep fused away).
// r7's proven double-buffered-kc structure, but the 16 KB per-kc fragment
// chunk is built from raw Wq/Wk (f32, L2-resident) by the block itself:
// thread tid loads W rows kc*32+(tid>>3), cols (tid&7)*8..+7 of both Wq and
// Wk, splits to bf16 hi/lo, and scatters into the SAME wbuf fragment layout
// wprep used: off = ct*1024 + lane_f*8 + j, lane_f = (rl>>3)*16 + (c&15),
// j = rl&7, ct = (c>>4) (+4 for Wk), lo at +512.
// Removes: wprep kernel, its launch gap, and the Wsp pi-buffer alias.
// ---------------------------------------------------------------------------
__global__ __launch_bounds__(256) void qk_mfma_kernel(
    const float* __restrict__ f, const float* __restrict__ log_eps,
    const float* __restrict__ Wq, const float* __restrict__ Wk,
    __hip_bfloat16* __restrict__ Qs, __hip_bfloat16* __restrict__ Ks)
{
    __shared__ __align__(16) u16 wbuf[2][8192];   // 2 x 16 KB kc-chunks

    const int tid  = threadIdx.x;
    const int wave = tid >> 6;
    const int lane = tid & 63;
    const int l15  = lane & 15, quad = lane >> 4;
    const int row0 = blockIdx.x * 64 + wave * 16; // this wave's 16-row tile
    const int b    = (blockIdx.x * 64) >> 11;     // blocks never straddle batch

    // W-conversion thread mapping (per kc chunk of 32 rows x 64 cols x 2 W)
    const int wrl = tid >> 3;                     // chunk-local row 0..31
    const int wc0 = (tid & 7) * 8;                // col start (one ct group)
    const int wct_q = wc0 >> 4;                   // ct for Wq elems (0..3)
    const int wj  = wrl & 7;
    const int wlane = (wrl >> 3) * 16;            // + (c&15) per element

    f32x4 acc[8] = {};
    const float* frow = f + (size_t)(row0 + l15) * DF + quad * 8;

#define WCONV(KC, DSTBUF)                                                      \
    {                                                                          \
        const float* wqp = Wq + (size_t)((KC) * 32 + wrl) * HH + wc0;          \
        const float* wkp = Wk + (size_t)((KC) * 32 + wrl) * HH + wc0;          \
        float4 q0 = *(const float4*)(wqp), q1 = *(const float4*)(wqp + 4);     \
        float4 k0 = *(const float4*)(wkp), k1 = *(const float4*)(wkp + 4);     \
        _Pragma("unroll")                                                      \
        for (int e = 0; e < 8; ++e) {                                          \
            float qv = (e < 4) ? (&q0.x)[e] : (&q1.x)[e - 4];                  \
            float kv = (e < 4) ? (&k0.x)[e] : (&k1.x)[e - 4];                  \
            int c15 = (wc0 + e) & 15;                                          \
            int offq = wct_q * 1024 + (wlane + c15) * 8 + wj;                  \
            int offk = (4 + wct_q) * 1024 + (wlane + c15) * 8 + wj;            \
            float hf, d;                                                       \
            short qh = bf_hi_bits(qv, &hf);                                    \
            short ql = bf_hi_bits(qv - hf, &d);                                \
            short kh = bf_hi_bits(kv, &hf);                                    \
            short kl = bf_hi_bits(kv - hf, &d);                                \
            DSTBUF[offq]       = (u16)qh;                                      \
            DSTBUF[offq + 512] = (u16)ql;                                      \
            DSTBUF[offk]       = (u16)kh;                                      \
            DSTBUF[offk + 512] = (u16)kl;                                      \
        }                                                                      \
    }

    // stage kc=0 fragments + first f fragments
    WCONV(0, wbuf[0]);
    float4 a0 = *(const float4*)(frow);
    float4 a1 = *(const float4*)(frow + 4);
    __syncthreads();

    for (int kc = 0; kc < 8; ++kc) {
        const int cur = kc & 1;
        float4 na0, na1;
        if (kc < 7) {
            na0 = *(const float4*)(frow + (kc + 1) * 32);
            na1 = *(const float4*)(frow + (kc + 1) * 32 + 4);
        }
        // A-fragment: row = l15, k = quad*8 + j (fp32 -> split bf16)
        bf16x8 ah, al;
#pragma unroll
        for (int e = 0; e < 4; ++e) {
            float hf, d;
            float v0 = (&a0.x)[e], v1 = (&a1.x)[e];
            ah[e]     = bf_hi_bits(v0, &hf);
            al[e]     = bf_hi_bits(v0 - hf, &d);
            ah[e + 4] = bf_hi_bits(v1, &hf);
            al[e + 4] = bf_hi_bits(v1 - hf, &d);
        }
#pragma unroll
        for (int ct = 0; ct < 8; ++ct) {
            bf16x8 bh = *(const bf16x8*)&wbuf[cur][ct * 1024 + lane * 8];
            bf16x8 bl = *(const bf16x8*)&wbuf[cur][ct * 1024 + 512 + lane * 8];
            acc[ct] = __builtin_amdgcn_mfma_f32_16x16x32_bf16(ah, bh, acc[ct], 0, 0, 0);
            acc[ct] = __builtin_amdgcn_mfma_f32_16x16x32_bf16(ah, bl, acc[ct], 0, 0, 0);
            acc[ct] = __builtin_amdgcn_mfma_f32_16x16x32_bf16(al, bh, acc[ct], 0, 0, 0);
        }
        if (kc < 7) {
            WCONV(kc + 1, wbuf[cur ^ 1]);
            a0 = na0; a1 = na1;
        }
        __syncthreads();
    }
#undef WCONV

    const float le = log_eps[b];
#pragma unroll
    for (int ct = 0; ct < 8; ++ct) {
        const int h = (ct & 3) * 16 + l15;
        const float wlast = (ct < 4 ? Wq : Wk)[DF * HH + h];
        __hip_bfloat16* out = (ct < 4) ? Qs : Ks;
        const float sc = (ct < 4) ? 0.125f : 1.0f;
#pragma unroll
        for (int r = 0; r < 4; ++r) {
            int bn = row0 + quad * 4 + r;         // C/D: col=l15, row=quad*4+r
            float v = (acc[ct][r] + le * wlast) * sc;
            __hip_bfloat16 hi = __float2bfloat16(v);
            __hip_bfloat16 lo = __float2bfloat16(v - __bfloat162float(hi));
            out[(size_t)bn * 128 + h]      = hi;
            out[(size_t)bn * 128 + 64 + h] = lo;
        }
    }
}

// ---------------------------------------------------------------------------
// Kernel 2: fused attention — r4/r7 proven version, byte-identical (64-col
// strips, 512 threads, 2 passes, plain pi stores, grid (32,8)).
// ---------------------------------------------------------------------------
__global__ __launch_bounds__(512, 2) void attn_kernel(
    const u16* __restrict__ Qs, const u16* __restrict__ Ks,
    const float* __restrict__ x, float* __restrict__ y, float* __restrict__ pi)
{
    __shared__ float xs[NN * 3];             // 24 KB: x for this batch
    __shared__ float cred[64];               // strip colsums
    __shared__ float yred[8 * 4 * 16 * 3];   // [wave][ct][col16][d], 6 KB

    const int tid   = threadIdx.x;
    const int strip = blockIdx.x;            // 0..31
    const int b     = blockIdx.y;            // 0..7
    const int m0    = strip * 64;
    const int wave  = tid >> 6;              // 0..7
    const int lane  = tid & 63;
    const int l15   = lane & 15;
    const int quad  = lane >> 4;

    if (tid < 64) cred[tid] = 0.f;
    for (int i = tid; i < NN * 3; i += 512) xs[i] = x[(size_t)b * NN * 3 + i];
    __syncthreads();

    // K-strip B-fragments (4 col-tiles), resident all kernel (~64 VGPR)
    bf16x8 bh[4][2], bl[4][2];
    {
        const u16* Kb = Ks + ((size_t)b * NN + m0) * 128;
#pragma unroll
        for (int ct = 0; ct < 4; ++ct) {
            const u16* kr = Kb + (size_t)(ct * 16 + l15) * 128;
#pragma unroll
            for (int ks = 0; ks < 2; ++ks) {
                int k0 = ks * 32 + quad * 8;
                bh[ct][ks] = *(const bf16x8*)(kr + k0);
                bl[ct][ks] = *(const bf16x8*)(kr + 64 + k0);
            }
        }
    }

    const u16* Qb = Qs + (size_t)b * NN * 128;
    float cs[4] = {0.f, 0.f, 0.f, 0.f};
    float yacc[4][3] = {};

    // ---- Pass 1: column sums + y accumulation ----
    for (int rt = 0; rt < 8; ++rt) {
#pragma unroll
        for (int sr = 0; sr < 2; ++sr) {
            const int row0 = rt * 256 + wave * 32 + sr * 16;
            const u16* qr = Qb + (size_t)(row0 + l15) * 128;
            bf16x8 ah[2], al[2];
#pragma unroll
            for (int ks = 0; ks < 2; ++ks) {
                int k0 = ks * 32 + quad * 8;
                ah[ks] = *(const bf16x8*)(qr + k0);
                al[ks] = *(const bf16x8*)(qr + 64 + k0);
            }
            float xv[4][3];
#pragma unroll
            for (int r = 0; r < 4; ++r) {
                int row = row0 + quad * 4 + r;
                xv[r][0] = xs[row * 3 + 0];
                xv[r][1] = xs[row * 3 + 1];
                xv[r][2] = xs[row * 3 + 2];
            }
#pragma unroll
            for (int ct = 0; ct < 4; ++ct) {
                f32x4 acc = {0.f, 0.f, 0.f, 0.f};
#pragma unroll
                for (int ks = 0; ks < 2; ++ks) {
                    acc = __builtin_amdgcn_mfma_f32_16x16x32_bf16(ah[ks], bh[ct][ks], acc, 0, 0, 0);
                    acc = __builtin_amdgcn_mfma_f32_16x16x32_bf16(ah[ks], bl[ct][ks], acc, 0, 0, 0);
                    acc = __builtin_amdgcn_mfma_f32_16x16x32_bf16(al[ks], bh[ct][ks], acc, 0, 0, 0);
                }
                float s = 0.f;
#pragma unroll
                for (int r = 0; r < 4; ++r) {
                    float v = __expf(acc[r]);
                    s += v;
                    yacc[ct][0] = fmaf(v, xv[r][0], yacc[ct][0]);
                    yacc[ct][1] = fmaf(v, xv[r][1], yacc[ct][1]);
                    yacc[ct][2] = fmaf(v, xv[r][2], yacc[ct][2]);
                }
                cs[ct] += s;
            }
        }
    }

    // deferred cross-quad reductions, then LDS
#pragma unroll
    for (int ct = 0; ct < 4; ++ct) {
        cs[ct] += __shfl_xor(cs[ct], 16);
        cs[ct] += __shfl_xor(cs[ct], 32);
#pragma unroll
        for (int d = 0; d < 3; ++d) {
            yacc[ct][d] += __shfl_xor(yacc[ct][d], 16);
            yacc[ct][d] += __shfl_xor(yacc[ct][d], 32);
        }
    }
    if (quad == 0) {
#pragma unroll
        for (int ct = 0; ct < 4; ++ct) {
            atomicAdd(&cred[ct * 16 + l15], cs[ct]);
#pragma unroll
            for (int d = 0; d < 3; ++d)
                yred[((wave * 4 + ct) * 16 + l15) * 3 + d] = yacc[ct][d];
        }
    }
    __syncthreads();

    if (tid < 192) {                         // 64 cols x 3 dims
        int c = tid / 3, d = tid - c * 3;
        int ct = c >> 4, cl = c & 15;
        float s = 0.f;
#pragma unroll
        for (int w = 0; w < 8; ++w)
            s += yred[((w * 4 + ct) * 16 + cl) * 3 + d];
        y[((size_t)b * NN + m0 + c) * 3 + d] = s / cred[c];
    }

    const float invN = 1.0f / (float)NN;
    float iv[4];
#pragma unroll
    for (int ct = 0; ct < 4; ++ct) iv[ct] = invN / cred[ct * 16 + l15];
    float* pib = pi + (size_t)b * NN * NN + m0;

    // ---- Pass 2: recompute, write pi (plain stores -> L2 coalesces) ----
    for (int rt = 0; rt < 8; ++rt) {
#pragma unroll
        for (int sr = 0; sr < 2; ++sr) {
            const int row0 = rt * 256 + wave * 32 + sr * 16;
            const u16* qr = Qb + (size_t)(row0 + l15) * 128;
            bf16x8 ah[2], al[2];
#pragma unroll
            for (int ks = 0; ks < 2; ++ks) {
                int k0 = ks * 32 + quad * 8;
                ah[ks] = *(const bf16x8*)(qr + k0);
                al[ks] = *(const bf16x8*)(qr + 64 + k0);
            }
#pragma unroll
            for (int ct = 0; ct < 4; ++ct) {
                f32x4 acc = {0.f, 0.f, 0.f, 0.f};
#pragma unroll
                for (int ks = 0; ks < 2; ++ks) {
                    acc = __builtin_amdgcn_mfma_f32_16x16x32_bf16(ah[ks], bh[ct][ks], acc, 0, 0, 0);
                    acc = __builtin_amdgcn_mfma_f32_16x16x32_bf16(ah[ks], bl[ct][ks], acc, 0, 0, 0);
                    acc = __builtin_amdgcn_mfma_f32_16x16x32_bf16(al[ks], bh[ct][ks], acc, 0, 0, 0);
                }
                float* op = pib + (size_t)(row0 + quad * 4) * NN + ct * 16 + l15;
#pragma unroll
                for (int r = 0; r < 4; ++r)
                    op[(size_t)r * NN] = __expf(acc[r]) * iv[ct];
            }
        }
    }
}

// ---------------------------------------------------------------------------
extern "C" void kernel_launch(void* const* d_in, const int* in_sizes, int n_in,
                              void* d_out, int out_size, void* d_ws, size_t ws_size,
                              hipStream_t stream) {
    const float* f  = (const float*)d_in[0];
    const float* x  = (const float*)d_in[1];
    const float* le = (const float*)d_in[2];
    const float* Wq = (const float*)d_in[3];
    const float* Wk = (const float*)d_in[4];

    float* y  = (float*)d_out;                       // (B, N, 3)
    float* pi = (float*)d_out + (size_t)BB * NN * 3; // (B, N, N)

    // Workspace: exactly the proven 8 MB (split-bf16 Q and K). No other
    // scratch: wprep is fused into qk (W converted per-block in LDS).
    __hip_bfloat16* Qs = (__hip_bfloat16*)d_ws;      // 4 MB
    __hip_bfloat16* Ks = Qs + (size_t)BB * NN * 128; // 4 MB

    qk_mfma_kernel<<<dim3(BB * NN / 64), 256, 0, stream>>>(f, le, Wq, Wk, Qs, Ks);
    attn_kernel<<<dim3(32, BB), 512, 0, stream>>>((const u16*)Qs, (const u16*)Ks,
                                                  x, y, pi);
}